// Round 6
// baseline (629.948 us; speedup 1.0000x reference)
//
#include <hip/hip_runtime.h>
#include <cstdint>
#include <stddef.h>

typedef short short8 __attribute__((ext_vector_type(8)));
typedef float floatx4 __attribute__((ext_vector_type(4)));
typedef unsigned short ushortx4 __attribute__((ext_vector_type(4)));

#define MFMA16(a, b, c) __builtin_amdgcn_mfma_f32_16x16x32_bf16((a), (b), (c), 0, 0, 0)

static constexpr int Bv = 2, Sv = 1536, Hv = 2048, NHv = 16, DHv = 128;
static constexpr int Mv = Bv * Sv;  // 3072
static constexpr float SCALE = 0.08838834764831845f;  // 1/sqrt(128), folded into Wq

// fp32 -> bf16 round-to-nearest-even
__device__ inline unsigned short f2bf(float f) {
  union { float f; unsigned u; } c; c.f = f;
  unsigned u = c.u;
  u += 0x7fffu + ((u >> 16) & 1u);
  return (unsigned short)(u >> 16);
}

// async global->LDS, 16B/lane; LDS dest must be wave-uniform (HW adds lane*16)
__device__ inline void async_copy16(const void* g, void* l) {
  auto gp = reinterpret_cast<__attribute__((address_space(1))) uint32_t*>(
      reinterpret_cast<uintptr_t>(g));
  auto lp = reinterpret_cast<__attribute__((address_space(3))) uint32_t*>(
      reinterpret_cast<uintptr_t>(l));
  __builtin_amdgcn_global_load_lds(gp, lp, 16, 0, 0);
}

// merged fp32->bf16 conversion for x + 4 weights (Wq pre-scaled by 1/sqrt(DH))
__global__ void cvt_all_kernel(const float* __restrict__ x,
    const float* __restrict__ Wq, const float* __restrict__ Wk,
    const float* __restrict__ Wv, const float* __restrict__ Wo,
    unsigned short* __restrict__ xb, unsigned short* __restrict__ wqb,
    unsigned short* __restrict__ wkb, unsigned short* __restrict__ wvb,
    unsigned short* __restrict__ wob) {
  const int i = blockIdx.x * 256 + threadIdx.x;
  const int nx4 = (Mv * Hv) / 4;
  const float* src; unsigned short* dst; int j; float scl = 1.0f;
  if (i < nx4) {
    src = x; dst = xb; j = i;
  } else {
    const int i2 = i - nx4;
    const int wsel = i2 >> 20;          // Hv*Hv/4 = 1<<20
    j = i2 & ((1 << 20) - 1);
    if (wsel == 0)      { src = Wq; dst = wqb; scl = SCALE; }
    else if (wsel == 1) { src = Wk; dst = wkb; }
    else if (wsel == 2) { src = Wv; dst = wvb; }
    else                { src = Wo; dst = wob; }
  }
  const float4 v = reinterpret_cast<const float4*>(src)[j];
  ushortx4 o;
  o[0] = f2bf(v.x * scl); o[1] = f2bf(v.y * scl);
  o[2] = f2bf(v.z * scl); o[3] = f2bf(v.w * scl);
  reinterpret_cast<ushortx4*>(dst)[j] = o;
}

// Fused QKV: {Q,K,V} = x @ W{q,k,v}^T. A staged ONCE per K-step, serves all three
// weight tiles. Single-buffered 2-barrier loop; LDS 64 KB -> 2 blocks/CU.
// 128x128 tiles, BK=64, 4 waves 2x2, XOR source-swizzled async staging.
__global__ __launch_bounds__(256, 2) void qkv_fused_kernel(
    const unsigned short* __restrict__ A,
    const unsigned short* __restrict__ Wq, const unsigned short* __restrict__ Wk,
    const unsigned short* __restrict__ Wv,
    unsigned short* __restrict__ Cq, unsigned short* __restrict__ Ck,
    unsigned short* __restrict__ Cv) {
  __shared__ __align__(16) unsigned short As[128 * 64];
  __shared__ __align__(16) unsigned short Bs[3][128 * 64];
  const int tid = threadIdx.x;
  const int w = tid >> 6, lane = tid & 63;
  const int quad = lane >> 4, l15 = lane & 15;
  const int wr = w >> 1, wc = w & 1;
  const int tileM = blockIdx.y * 128, tileN = blockIdx.x * 128;

  floatx4 aq[4][4], ak[4][4], av[4][4];
#pragma unroll
  for (int i = 0; i < 4; ++i)
#pragma unroll
    for (int j = 0; j < 4; ++j)
#pragma unroll
      for (int r = 0; r < 4; ++r) { aq[i][j][r] = 0.0f; ak[i][j][r] = 0.0f; av[i][j][r] = 0.0f; }

  // staging descriptors: slot = m*256+tid; row = slot>>3; blk = slot&7 (8x16B per row)
  size_t aoff[4], boff[4]; int lbs[4];
#pragma unroll
  for (int m = 0; m < 4; ++m) {
    const int slot = m * 256 + tid;
    const int row = slot >> 3, blk = slot & 7;
    const int sw = (blk ^ (row & 7)) * 8;
    aoff[m] = (size_t)(tileM + row) * 2048 + sw;
    boff[m] = (size_t)(tileN + row) * 2048 + sw;
    lbs[m] = (m * 256 + w * 64) * 8;  // wave-uniform
  }

  for (int k0 = 0; k0 < 2048; k0 += 64) {
    __syncthreads();
#pragma unroll
    for (int m = 0; m < 4; ++m) async_copy16(A + aoff[m] + k0, As + lbs[m]);
#pragma unroll
    for (int m = 0; m < 4; ++m) async_copy16(Wq + boff[m] + k0, Bs[0] + lbs[m]);
#pragma unroll
    for (int m = 0; m < 4; ++m) async_copy16(Wk + boff[m] + k0, Bs[1] + lbs[m]);
#pragma unroll
    for (int m = 0; m < 4; ++m) async_copy16(Wv + boff[m] + k0, Bs[2] + lbs[m]);
    __syncthreads();
#pragma unroll
    for (int kk = 0; kk < 2; ++kk) {
      const int swz = (((kk * 4 + quad) ^ (l15 & 7)) * 8);
      short8 af[4];
#pragma unroll
      for (int i = 0; i < 4; ++i)
        af[i] = *(const short8*)(As + (wr * 64 + i * 16 + l15) * 64 + swz);
      {
        short8 bq[4];
#pragma unroll
        for (int j = 0; j < 4; ++j)
          bq[j] = *(const short8*)(Bs[0] + (wc * 64 + j * 16 + l15) * 64 + swz);
#pragma unroll
        for (int i = 0; i < 4; ++i)
#pragma unroll
          for (int j = 0; j < 4; ++j) aq[i][j] = MFMA16(af[i], bq[j], aq[i][j]);
      }
      {
        short8 bk[4];
#pragma unroll
        for (int j = 0; j < 4; ++j)
          bk[j] = *(const short8*)(Bs[1] + (wc * 64 + j * 16 + l15) * 64 + swz);
#pragma unroll
        for (int i = 0; i < 4; ++i)
#pragma unroll
          for (int j = 0; j < 4; ++j) ak[i][j] = MFMA16(af[i], bk[j], ak[i][j]);
      }
      {
        short8 bv[4];
#pragma unroll
        for (int j = 0; j < 4; ++j)
          bv[j] = *(const short8*)(Bs[2] + (wc * 64 + j * 16 + l15) * 64 + swz);
#pragma unroll
        for (int i = 0; i < 4; ++i)
#pragma unroll
          for (int j = 0; j < 4; ++j) av[i][j] = MFMA16(af[i], bv[j], av[i][j]);
      }
    }
  }

#pragma unroll
  for (int i = 0; i < 4; ++i) {
#pragma unroll
    for (int r = 0; r < 4; ++r) {
      const size_t row = tileM + wr * 64 + i * 16 + quad * 4 + r;
#pragma unroll
      for (int j = 0; j < 4; ++j) {
        const int col = tileN + wc * 64 + j * 16 + l15;
        Cq[row * 2048 + col] = f2bf(aq[i][j][r]);
        Ck[row * 2048 + col] = f2bf(ak[i][j][r]);
        Cv[row * 2048 + col] = f2bf(av[i][j][r]);
      }
    }
  }
}

// C = A @ W^T. A: Mx2048 bf16 rm, W: 2048x2048 bf16 rm. TM x 128 tiles, BK=64.
// 4 waves in 2x2; XOR source-swizzled async staging; 2-phase dbuf pipeline.
template <int TM, bool WF32>
__global__ __launch_bounds__(256) void gemm_bt_kernel(
    const unsigned short* __restrict__ A,
    const unsigned short* __restrict__ W0,
    void* __restrict__ C0) {
  constexpr int MI = TM / 32;  // M-frags per wave (4 or 2)
  __shared__ __align__(16) unsigned short As[2][TM * 64];
  __shared__ __align__(16) unsigned short Bs[2][128 * 64];
  const unsigned short* W = W0;
  const int tid = threadIdx.x;
  const int w = tid >> 6, lane = tid & 63;
  const int quad = lane >> 4, l15 = lane & 15;
  const int wr = w >> 1, wc = w & 1;
  const int tileM = blockIdx.y * TM, tileN = blockIdx.x * 128;

  floatx4 acc[MI][4];
#pragma unroll
  for (int i = 0; i < MI; ++i)
#pragma unroll
    for (int j = 0; j < 4; ++j)
#pragma unroll
      for (int r = 0; r < 4; ++r) acc[i][j][r] = 0.0f;

  // staging descriptors: slot = m*256+tid; row = slot>>3; blk = slot&7 (8x16B per row)
  size_t aoff[MI]; int alb[MI];
#pragma unroll
  for (int m = 0; m < MI; ++m) {
    const int slot = m * 256 + tid;
    const int row = slot >> 3, blk = slot & 7;
    aoff[m] = (size_t)(tileM + row) * 2048 + ((blk ^ (row & 7)) * 8);
    alb[m] = (m * 256 + w * 64) * 8;  // wave-uniform
  }
  size_t boff[4]; int blb[4];
#pragma unroll
  for (int m = 0; m < 4; ++m) {
    const int slot = m * 256 + tid;
    const int row = slot >> 3, blk = slot & 7;
    boff[m] = (size_t)(tileN + row) * 2048 + ((blk ^ (row & 7)) * 8);
    blb[m] = (m * 256 + w * 64) * 8;
  }

  // prologue: stage tile 0 into buffer 0
#pragma unroll
  for (int m = 0; m < MI; ++m) async_copy16(A + aoff[m], As[0] + alb[m]);
#pragma unroll
  for (int m = 0; m < 4; ++m) async_copy16(W + boff[m], Bs[0] + blb[m]);
  __syncthreads();

  for (int t = 0; t < 32; ++t) {
    const int cur = t & 1;
    if (t < 31) {
      const int kn = (t + 1) * 64;
#pragma unroll
      for (int m = 0; m < MI; ++m)
        async_copy16(A + aoff[m] + kn, As[cur ^ 1] + alb[m]);
#pragma unroll
      for (int m = 0; m < 4; ++m)
        async_copy16(W + boff[m] + kn, Bs[cur ^ 1] + blb[m]);
    }
    const unsigned short* as_ = As[cur];
    const unsigned short* bs_ = Bs[cur];
#pragma unroll
    for (int kk = 0; kk < 2; ++kk) {
      const int swz = (((kk * 4 + quad) ^ (l15 & 7)) * 8);
      short8 af[MI], bfr[4];
#pragma unroll
      for (int i = 0; i < MI; ++i)
        af[i] = *(const short8*)(as_ + (wr * (TM / 2) + i * 16 + l15) * 64 + swz);
#pragma unroll
      for (int j = 0; j < 4; ++j)
        bfr[j] = *(const short8*)(bs_ + (wc * 64 + j * 16 + l15) * 64 + swz);
#pragma unroll
      for (int i = 0; i < MI; ++i)
#pragma unroll
        for (int j = 0; j < 4; ++j) acc[i][j] = MFMA16(af[i], bfr[j], acc[i][j]);
    }
    __syncthreads();  // reads of buf[cur] done; next-tile loads have landed
  }

  void* C = C0;
#pragma unroll
  for (int i = 0; i < MI; ++i) {
#pragma unroll
    for (int r = 0; r < 4; ++r) {
      const int row = tileM + wr * (TM / 2) + i * 16 + quad * 4 + r;
#pragma unroll
      for (int j = 0; j < 4; ++j) {
        const int col = tileN + wc * 64 + j * 16 + l15;
        if (WF32)
          ((float*)C)[(size_t)row * 2048 + col] = acc[i][j][r];
        else
          ((unsigned short*)C)[(size_t)row * 2048 + col] = f2bf(acc[i][j][r]);
      }
    }
  }
}

// V [b*S, h*128+d] -> Vt [b,h,d,k] (bf16), LDS-tiled transpose
__global__ __launch_bounds__(256) void vtrans_kernel(
    const unsigned short* __restrict__ V, unsigned short* __restrict__ Vtg) {
  __shared__ unsigned short Vs[64 * 132];  // pad 132: 2-way-free column reads
  const int t0 = blockIdx.x * 64, h = blockIdx.y, b = blockIdx.z;
  const int tid = threadIdx.x;
  const int w = tid >> 6, lane = tid & 63;
#pragma unroll
  for (int m = 0; m < 4; ++m) {
    const int idx = m * 256 + tid;
    const int tr = idx >> 4, blk = idx & 15;
    const unsigned short* src = V + ((size_t)(b * Sv) + t0 + tr) * Hv + h * DHv + blk * 8;
    ushortx4 v0 = *(const ushortx4*)(src);
    ushortx4 v1 = *(const ushortx4*)(src + 4);
    *(ushortx4*)(Vs + tr * 132 + blk * 8) = v0;      // 8B-aligned (132*2=264)
    *(ushortx4*)(Vs + tr * 132 + blk * 8 + 4) = v1;
  }
  __syncthreads();
  const size_t obase = ((size_t)(b * NHv + h) * DHv) * Sv + t0;
#pragma unroll 4
  for (int p = 0; p < 32; ++p) {
    const int d = p * 4 + w;
    Vtg[obase + (size_t)d * Sv + lane] = Vs[lane * 132 + d];
  }
}

// Flash attention, bias + causal, NO-MAX softmax (logits bounded; exp<=e^10 fp32-safe).
// QBLK=128: 128 Q rows/block, 4 waves x 2 row-groups x 16 rows (sequential groups,
// shared per-wave P buffer -- per-wave LDS ops are in-order). K/Vt double-buffered,
// staged one tile ahead; halves staging events + barriers per unit work vs QBLK=64.
// g0 bias prefetched one tile ahead (latency-critical); g1 bias loaded at iter start
// (consumed ~1000 cyc later, self-hiding). Fully-masked g0 tail tile skipped.
__global__ __launch_bounds__(256, 2) void attn_kernel(
    const unsigned short* __restrict__ Qg, const unsigned short* __restrict__ Kg,
    const unsigned short* __restrict__ Vtg, const float* __restrict__ bias,
    unsigned short* __restrict__ Og) {
  __shared__ __align__(16) unsigned short Ks[2][64 * 128];   // [key][d], 16-blk swizzle
  __shared__ __align__(16) unsigned short Vt[2][128 * 64];   // [d][key], 8-blk swizzle
  __shared__ __align__(16) unsigned short Ps[4 * 16 * 64];   // per-wave, reused by groups

  const int xb = blockIdx.x;                 // 12 q-tiles of 128 rows
  const int qt = (xb & 1) ? (11 - (xb >> 1)) : (xb >> 1);
  const int h = blockIdx.y, b = blockIdx.z;
  const int q0 = qt * 128;
  const int tid = threadIdx.x;
  const int w = tid >> 6, lane = tid & 63;
  const int quad = lane >> 4, l15 = lane & 15;

  const size_t bh_base = (size_t)(b * Sv) * Hv + (size_t)h * DHv;
  const size_t vt_base = ((size_t)(b * NHv + h) * DHv) * Sv;

  // Q frags (A-operand), 2 row-groups: row = q0 + g*64 + w*16 + l15
  short8 qf[2][4];
#pragma unroll
  for (int g = 0; g < 2; ++g) {
    const unsigned short* qbase =
        Qg + bh_base + (size_t)(q0 + g * 64 + w * 16 + l15) * Hv;
#pragma unroll
    for (int kk = 0; kk < 4; ++kk)
      qf[g][kk] = *(const short8*)(qbase + kk * 32 + quad * 8);
  }

  floatx4 o[2][8];
#pragma unroll
  for (int g = 0; g < 2; ++g)
#pragma unroll
    for (int n = 0; n < 8; ++n)
#pragma unroll
      for (int r = 0; r < 4; ++r) o[g][n][r] = 0.0f;
  float lrow[2][4] = {{0.0f, 0.0f, 0.0f, 0.0f}, {0.0f, 0.0f, 0.0f, 0.0f}};

  const float* biasbase = bias + (size_t)(b * NHv + h) * Sv * Sv;
  unsigned short* pw = Ps + w * 1024;

  // staging descriptors (unchanged tile shapes)
  size_t koff[4], voff[4]; int lbs[4];
#pragma unroll
  for (int m = 0; m < 4; ++m) {
    const int sK = m * 256 + tid;
    const int rK = sK >> 4, bK = sK & 15;          // Ks: 64 rows x 16 blocks
    koff[m] = bh_base + (size_t)rK * Hv + ((bK ^ (rK & 15)) * 8);
    const int sV = m * 256 + tid;
    const int rV = sV >> 3, bV = sV & 7;           // Vt: 128 rows x 8 blocks
    voff[m] = vt_base + (size_t)rV * Sv + ((bV ^ (rV & 7)) * 8);
    lbs[m] = (m * 256 + w * 64) * 8;               // wave-uniform
  }

  // g0 bias prefetch for tile 0
  float bv0n[4][4];
#pragma unroll
  for (int r = 0; r < 4; ++r) {
    const size_t brow = (size_t)(q0 + w * 16 + quad * 4 + r) * Sv;
#pragma unroll
    for (int j = 0; j < 4; ++j) bv0n[r][j] = biasbase[brow + j * 16 + l15];
  }

  // prologue: stage KV tile 0 into buffer 0
#pragma unroll
  for (int m = 0; m < 4; ++m) {
    async_copy16(Kg + koff[m], Ks[0] + lbs[m]);
    async_copy16(Vtg + voff[m], Vt[0] + lbs[m]);
  }
  __syncthreads();

  const int nkt = 2 * qt + 2;
  for (int kt = 0; kt < nkt; ++kt) {
    const int k0 = kt * 64;
    const int cur = kt & 1;

    // stage next KV tile into the other buffer (in flight across compute)
    if (kt + 1 < nkt) {
      const int k1 = k0 + 64;
#pragma unroll
      for (int m = 0; m < 4; ++m) {
        async_copy16(Kg + koff[m] + (size_t)k1 * Hv, Ks[cur ^ 1] + lbs[m]);
        async_copy16(Vtg + voff[m] + k1, Vt[cur ^ 1] + lbs[m]);
      }
    }

    // bias: g0 from prefetch; g1 loaded now (consumed after g0's QK+SM+PV);
    // re-prefetch g0 for the next tile
    float bv[2][4][4];
#pragma unroll
    for (int r = 0; r < 4; ++r)
#pragma unroll
      for (int j = 0; j < 4; ++j) bv[0][r][j] = bv0n[r][j];
#pragma unroll
    for (int r = 0; r < 4; ++r) {
      const size_t brow = (size_t)(q0 + 64 + w * 16 + quad * 4 + r) * Sv;
#pragma unroll
      for (int j = 0; j < 4; ++j) bv[1][r][j] = biasbase[brow + k0 + j * 16 + l15];
    }
    const int knext = (kt + 1 < nkt) ? k0 + 64 : k0;
#pragma unroll
    for (int r = 0; r < 4; ++r) {
      const size_t brow = (size_t)(q0 + w * 16 + quad * 4 + r) * Sv;
#pragma unroll
      for (int j = 0; j < 4; ++j) bv0n[r][j] = biasbase[brow + knext + j * 16 + l15];
    }

    const unsigned short* ks_ = Ks[cur];
    const unsigned short* vt_ = Vt[cur];

#pragma unroll
    for (int g = 0; g < 2; ++g) {
      const int rbase = q0 + g * 64;
      if (k0 == rbase + 64) continue;   // fully-masked (g=0 on the last tile only)
      const bool diag = (k0 == rbase);

      // S = Q K^T
      floatx4 sacc[4];
      __builtin_amdgcn_s_setprio(1);
#pragma unroll
      for (int j = 0; j < 4; ++j) {
#pragma unroll
        for (int r = 0; r < 4; ++r) sacc[j][r] = 0.0f;
        const int kr = j * 16 + l15;
#pragma unroll
        for (int kk = 0; kk < 4; ++kk) {
          const int gq = kk * 4 + quad;
          short8 bfrag = *(const short8*)(ks_ + kr * 128 + (gq ^ (kr & 15)) * 8);
          sacc[j] = MFMA16(qf[g][kk], bfrag, sacc[j]);
        }
      }
      __builtin_amdgcn_s_setprio(0);

      // p = exp(s + bias) (no max-shift), causal zero on diagonal tile; store P
#pragma unroll
      for (int r = 0; r < 4; ++r) {
        const int qrow = rbase + w * 16 + quad * 4 + r;
        const int prow = quad * 4 + r;
        float acc_l = 0.0f;
#pragma unroll
        for (int j = 0; j < 4; ++j) {
          const int col = j * 16 + l15;
          float p = __expf(sacc[j][r] + bv[g][r][j]);
          if (diag && (k0 + col) > qrow) p = 0.0f;
          acc_l += p;
          pw[prow * 64 + ((col >> 3) ^ (prow & 7)) * 8 + (col & 7)] = f2bf(p);
        }
        lrow[g][r] += acc_l;
      }

      // O += P @ V  (per-wave in-order LDS: P write->read needs no barrier)
      __builtin_amdgcn_s_setprio(1);
#pragma unroll
      for (int kk = 0; kk < 2; ++kk) {
        const int gq = kk * 4 + quad;
        short8 pa = *(const short8*)(pw + l15 * 64 + (gq ^ (l15 & 7)) * 8);
#pragma unroll
        for (int n = 0; n < 8; ++n) {
          const int dr = n * 16 + l15;
          short8 vbf = *(const short8*)(vt_ + dr * 64 + (gq ^ (dr & 7)) * 8);
          o[g][n] = MFMA16(pa, vbf, o[g][n]);
        }
      }
      __builtin_amdgcn_s_setprio(0);
    }

    __syncthreads();  // KV[cur] reads done; next tile's loads have landed
  }

  // epilogue: reduce l across the 16 lanes holding each row, normalize, store
#pragma unroll
  for (int g = 0; g < 2; ++g) {
#pragma unroll
    for (int r = 0; r < 4; ++r) {
      float ls = lrow[g][r];
#pragma unroll
      for (int off = 1; off < 16; off <<= 1) ls += __shfl_xor(ls, off, 64);
      const float inv = 1.0f / ls;
      const int qrow = q0 + g * 64 + w * 16 + quad * 4 + r;
      const size_t rowbase = bh_base + (size_t)qrow * Hv;
#pragma unroll
      for (int n = 0; n < 8; ++n)
        Og[rowbase + n * 16 + l15] = f2bf(o[g][n][r] * inv);
    }
  }
}

extern "C" void kernel_launch(void* const* d_in, const int* in_sizes, int n_in,
                              void* d_out, int out_size, void* d_ws, size_t ws_size,
                              hipStream_t stream) {
  const float* x = (const float*)d_in[0];
  const float* bias = (const float*)d_in[1];
  const float* Wq = (const float*)d_in[2];
  const float* Wk = (const float*)d_in[3];
  const float* Wv = (const float*)d_in[4];
  const float* Wo = (const float*)d_in[5];
  float* out = (float*)d_out;

  unsigned short* xb = (unsigned short*)d_ws;          // xb reused as Vt after QKV GEMM
  unsigned short* wqb = xb + (size_t)Mv * Hv;
  unsigned short* wkb = wqb + (size_t)Hv * Hv;
  unsigned short* wvb = wkb + (size_t)Hv * Hv;
  unsigned short* wob = wvb + (size_t)Hv * Hv;
  unsigned short* qb = wob + (size_t)Hv * Hv;
  unsigned short* kb = qb + (size_t)Mv * Hv;
  unsigned short* vb = kb + (size_t)Mv * Hv;
  unsigned short* ob = vb + (size_t)Mv * Hv;
  unsigned short* vtb = xb;  // x bf16 is dead after the QKV GEMM
  const size_t needed = ((size_t)Mv * Hv * 5 + (size_t)Hv * Hv * 4) * 2;
  if (ws_size < needed) return;

  const int cvt_n = (Mv * Hv) / 4 + Hv * Hv;
  cvt_all_kernel<<<dim3(cvt_n / 256), 256, 0, stream>>>(
      x, Wq, Wk, Wv, Wo, xb, wqb, wkb, wvb, wob);

  // Q,K,V = x @ W{q,k,v}^T (bf16 out), fused: A staged once for all three weights
  qkv_fused_kernel<<<dim3(16, 24), 256, 0, stream>>>(
      xb, wqb, wkb, wvb, qb, kb, vb);

  // global V^T for async attention staging
  vtrans_kernel<<<dim3(24, 16, 2), 256, 0, stream>>>(vb, vtb);

  // 128 Q rows per block -> 12 q-tiles
  attn_kernel<<<dim3(12, NHv, Bv), 256, 0, stream>>>(qb, kb, vtb, bias, ob);

  // out = attn @ Wo^T (fp32), 128x128 tiles -> 384 blocks
  gemm_bt_kernel<128, true><<<dim3(16, 24), 256, 0, stream>>>(ob, wob, out);
}

// Round 10
// 579.337 us; speedup vs baseline: 1.0874x; 1.0874x over previous
//
#include <hip/hip_runtime.h>
#include <cstdint>
#include <stddef.h>

typedef short short8 __attribute__((ext_vector_type(8)));
typedef float floatx4 __attribute__((ext_vector_type(4)));
typedef unsigned short ushortx4 __attribute__((ext_vector_type(4)));

#define MFMA16(a, b, c) __builtin_amdgcn_mfma_f32_16x16x32_bf16((a), (b), (c), 0, 0, 0)

static constexpr int Bv = 2, Sv = 1536, Hv = 2048, NHv = 16, DHv = 128;
static constexpr int Mv = Bv * Sv;  // 3072
static constexpr float SCALE = 0.08838834764831845f;  // 1/sqrt(128), folded into Wq

// fp32 -> bf16 round-to-nearest-even
__device__ inline unsigned short f2bf(float f) {
  union { float f; unsigned u; } c; c.f = f;
  unsigned u = c.u;
  u += 0x7fffu + ((u >> 16) & 1u);
  return (unsigned short)(u >> 16);
}

// async global->LDS, 16B/lane; LDS dest must be wave-uniform (HW adds lane*16)
__device__ inline void async_copy16(const void* g, void* l) {
  auto gp = reinterpret_cast<__attribute__((address_space(1))) uint32_t*>(
      reinterpret_cast<uintptr_t>(g));
  auto lp = reinterpret_cast<__attribute__((address_space(3))) uint32_t*>(
      reinterpret_cast<uintptr_t>(l));
  __builtin_amdgcn_global_load_lds(gp, lp, 16, 0, 0);
}

// merged fp32->bf16 conversion for x + 4 weights (Wq pre-scaled by 1/sqrt(DH))
__global__ void cvt_all_kernel(const float* __restrict__ x,
    const float* __restrict__ Wq, const float* __restrict__ Wk,
    const float* __restrict__ Wv, const float* __restrict__ Wo,
    unsigned short* __restrict__ xb, unsigned short* __restrict__ wqb,
    unsigned short* __restrict__ wkb, unsigned short* __restrict__ wvb,
    unsigned short* __restrict__ wob) {
  const int i = blockIdx.x * 256 + threadIdx.x;
  const int nx4 = (Mv * Hv) / 4;
  const float* src; unsigned short* dst; int j; float scl = 1.0f;
  if (i < nx4) {
    src = x; dst = xb; j = i;
  } else {
    const int i2 = i - nx4;
    const int wsel = i2 >> 20;          // Hv*Hv/4 = 1<<20
    j = i2 & ((1 << 20) - 1);
    if (wsel == 0)      { src = Wq; dst = wqb; scl = SCALE; }
    else if (wsel == 1) { src = Wk; dst = wkb; }
    else if (wsel == 2) { src = Wv; dst = wvb; }
    else                { src = Wo; dst = wob; }
  }
  const float4 v = reinterpret_cast<const float4*>(src)[j];
  ushortx4 o;
  o[0] = f2bf(v.x * scl); o[1] = f2bf(v.y * scl);
  o[2] = f2bf(v.z * scl); o[3] = f2bf(v.w * scl);
  reinterpret_cast<ushortx4*>(dst)[j] = o;
}

// Fused QKV: {Q,K,V} = x @ W{q,k,v}^T. A staged ONCE per K-step, serves all three
// weight tiles. Single-buffered 2-barrier loop; LDS 60 KB -> 2 blocks/CU.
// BM=96 x BN=128 tiles -> grid 32x16 = 512 blocks = EXACTLY 2/CU (balanced:
// the prior 128x128 / 384-block grid ran half the CUs at 2 blocks and half at 1,
// putting the critical path at 75% machine utilization).
__global__ __launch_bounds__(256, 2) void qkv_fused_kernel(
    const unsigned short* __restrict__ A,
    const unsigned short* __restrict__ Wq, const unsigned short* __restrict__ Wk,
    const unsigned short* __restrict__ Wv,
    unsigned short* __restrict__ Cq, unsigned short* __restrict__ Ck,
    unsigned short* __restrict__ Cv) {
  __shared__ __align__(16) unsigned short As[96 * 64];
  __shared__ __align__(16) unsigned short Bs[3][128 * 64];
  const int tid = threadIdx.x;
  const int w = tid >> 6, lane = tid & 63;
  const int quad = lane >> 4, l15 = lane & 15;
  const int wr = w >> 1, wc = w & 1;
  const int tileM = blockIdx.y * 96, tileN = blockIdx.x * 128;

  floatx4 aq[3][4], ak[3][4], av[3][4];
#pragma unroll
  for (int i = 0; i < 3; ++i)
#pragma unroll
    for (int j = 0; j < 4; ++j)
#pragma unroll
      for (int r = 0; r < 4; ++r) { aq[i][j][r] = 0.0f; ak[i][j][r] = 0.0f; av[i][j][r] = 0.0f; }

  // staging descriptors: slot = m*256+tid; row = slot>>3; blk = slot&7 (8x16B per row)
  size_t aoff[3]; int alb[3];
#pragma unroll
  for (int m = 0; m < 3; ++m) {
    const int slot = m * 256 + tid;
    const int row = slot >> 3, blk = slot & 7;
    aoff[m] = (size_t)(tileM + row) * 2048 + ((blk ^ (row & 7)) * 8);
    alb[m] = (m * 256 + w * 64) * 8;  // wave-uniform
  }
  size_t boff[4]; int blb[4];
#pragma unroll
  for (int m = 0; m < 4; ++m) {
    const int slot = m * 256 + tid;
    const int row = slot >> 3, blk = slot & 7;
    boff[m] = (size_t)(tileN + row) * 2048 + ((blk ^ (row & 7)) * 8);
    blb[m] = (m * 256 + w * 64) * 8;
  }

  for (int k0 = 0; k0 < 2048; k0 += 64) {
    __syncthreads();
#pragma unroll
    for (int m = 0; m < 3; ++m) async_copy16(A + aoff[m] + k0, As + alb[m]);
#pragma unroll
    for (int m = 0; m < 4; ++m) async_copy16(Wq + boff[m] + k0, Bs[0] + blb[m]);
#pragma unroll
    for (int m = 0; m < 4; ++m) async_copy16(Wk + boff[m] + k0, Bs[1] + blb[m]);
#pragma unroll
    for (int m = 0; m < 4; ++m) async_copy16(Wv + boff[m] + k0, Bs[2] + blb[m]);
    __syncthreads();
#pragma unroll
    for (int kk = 0; kk < 2; ++kk) {
      const int swz = (((kk * 4 + quad) ^ (l15 & 7)) * 8);
      short8 af[3];
#pragma unroll
      for (int i = 0; i < 3; ++i)
        af[i] = *(const short8*)(As + (wr * 48 + i * 16 + l15) * 64 + swz);
      {
        short8 bq[4];
#pragma unroll
        for (int j = 0; j < 4; ++j)
          bq[j] = *(const short8*)(Bs[0] + (wc * 64 + j * 16 + l15) * 64 + swz);
#pragma unroll
        for (int i = 0; i < 3; ++i)
#pragma unroll
          for (int j = 0; j < 4; ++j) aq[i][j] = MFMA16(af[i], bq[j], aq[i][j]);
      }
      {
        short8 bk[4];
#pragma unroll
        for (int j = 0; j < 4; ++j)
          bk[j] = *(const short8*)(Bs[1] + (wc * 64 + j * 16 + l15) * 64 + swz);
#pragma unroll
        for (int i = 0; i < 3; ++i)
#pragma unroll
          for (int j = 0; j < 4; ++j) ak[i][j] = MFMA16(af[i], bk[j], ak[i][j]);
      }
      {
        short8 bv[4];
#pragma unroll
        for (int j = 0; j < 4; ++j)
          bv[j] = *(const short8*)(Bs[2] + (wc * 64 + j * 16 + l15) * 64 + swz);
#pragma unroll
        for (int i = 0; i < 3; ++i)
#pragma unroll
          for (int j = 0; j < 4; ++j) av[i][j] = MFMA16(af[i], bv[j], av[i][j]);
      }
    }
  }

#pragma unroll
  for (int i = 0; i < 3; ++i) {
#pragma unroll
    for (int r = 0; r < 4; ++r) {
      const size_t row = tileM + wr * 48 + i * 16 + quad * 4 + r;
#pragma unroll
      for (int j = 0; j < 4; ++j) {
        const int col = tileN + wc * 64 + j * 16 + l15;
        Cq[row * 2048 + col] = f2bf(aq[i][j][r]);
        Ck[row * 2048 + col] = f2bf(ak[i][j][r]);
        Cv[row * 2048 + col] = f2bf(av[i][j][r]);
      }
    }
  }
}

// C = A @ W^T. A: Mx2048 bf16 rm, W: 2048x2048 bf16 rm. TM x 128 tiles, BK=64.
// 4 waves in 2x2; XOR source-swizzled async staging; 2-phase dbuf pipeline.
// TM=96 -> 512-block balanced grid (2/CU exactly).
template <int TM, bool WF32>
__global__ __launch_bounds__(256) void gemm_bt_kernel(
    const unsigned short* __restrict__ A,
    const unsigned short* __restrict__ W0,
    void* __restrict__ C0) {
  constexpr int MI = TM / 32;  // M-frags per wave
  __shared__ __align__(16) unsigned short As[2][TM * 64];
  __shared__ __align__(16) unsigned short Bs[2][128 * 64];
  const unsigned short* W = W0;
  const int tid = threadIdx.x;
  const int w = tid >> 6, lane = tid & 63;
  const int quad = lane >> 4, l15 = lane & 15;
  const int wr = w >> 1, wc = w & 1;
  const int tileM = blockIdx.y * TM, tileN = blockIdx.x * 128;

  floatx4 acc[MI][4];
#pragma unroll
  for (int i = 0; i < MI; ++i)
#pragma unroll
    for (int j = 0; j < 4; ++j)
#pragma unroll
      for (int r = 0; r < 4; ++r) acc[i][j][r] = 0.0f;

  // staging descriptors: slot = m*256+tid; row = slot>>3; blk = slot&7 (8x16B per row)
  size_t aoff[MI]; int alb[MI];
#pragma unroll
  for (int m = 0; m < MI; ++m) {
    const int slot = m * 256 + tid;
    const int row = slot >> 3, blk = slot & 7;
    aoff[m] = (size_t)(tileM + row) * 2048 + ((blk ^ (row & 7)) * 8);
    alb[m] = (m * 256 + w * 64) * 8;  // wave-uniform
  }
  size_t boff[4]; int blb[4];
#pragma unroll
  for (int m = 0; m < 4; ++m) {
    const int slot = m * 256 + tid;
    const int row = slot >> 3, blk = slot & 7;
    boff[m] = (size_t)(tileN + row) * 2048 + ((blk ^ (row & 7)) * 8);
    blb[m] = (m * 256 + w * 64) * 8;
  }

  // prologue: stage tile 0 into buffer 0
#pragma unroll
  for (int m = 0; m < MI; ++m) async_copy16(A + aoff[m], As[0] + alb[m]);
#pragma unroll
  for (int m = 0; m < 4; ++m) async_copy16(W + boff[m], Bs[0] + blb[m]);
  __syncthreads();

  for (int t = 0; t < 32; ++t) {
    const int cur = t & 1;
    if (t < 31) {
      const int kn = (t + 1) * 64;
#pragma unroll
      for (int m = 0; m < MI; ++m)
        async_copy16(A + aoff[m] + kn, As[cur ^ 1] + alb[m]);
#pragma unroll
      for (int m = 0; m < 4; ++m)
        async_copy16(W + boff[m] + kn, Bs[cur ^ 1] + blb[m]);
    }
    const unsigned short* as_ = As[cur];
    const unsigned short* bs_ = Bs[cur];
#pragma unroll
    for (int kk = 0; kk < 2; ++kk) {
      const int swz = (((kk * 4 + quad) ^ (l15 & 7)) * 8);
      short8 af[MI], bfr[4];
#pragma unroll
      for (int i = 0; i < MI; ++i)
        af[i] = *(const short8*)(as_ + (wr * (TM / 2) + i * 16 + l15) * 64 + swz);
#pragma unroll
      for (int j = 0; j < 4; ++j)
        bfr[j] = *(const short8*)(bs_ + (wc * 64 + j * 16 + l15) * 64 + swz);
#pragma unroll
      for (int i = 0; i < MI; ++i)
#pragma unroll
        for (int j = 0; j < 4; ++j) acc[i][j] = MFMA16(af[i], bfr[j], acc[i][j]);
    }
    __syncthreads();  // reads of buf[cur] done; next-tile loads have landed
  }

  void* C = C0;
#pragma unroll
  for (int i = 0; i < MI; ++i) {
#pragma unroll
    for (int r = 0; r < 4; ++r) {
      const int row = tileM + wr * (TM / 2) + i * 16 + quad * 4 + r;
#pragma unroll
      for (int j = 0; j < 4; ++j) {
        const int col = tileN + wc * 64 + j * 16 + l15;
        if (WF32)
          ((float*)C)[(size_t)row * 2048 + col] = acc[i][j][r];
        else
          ((unsigned short*)C)[(size_t)row * 2048 + col] = f2bf(acc[i][j][r]);
      }
    }
  }
}

// V [b*S, h*128+d] -> Vt [b,h,d,k] (bf16), LDS-tiled transpose
__global__ __launch_bounds__(256) void vtrans_kernel(
    const unsigned short* __restrict__ V, unsigned short* __restrict__ Vtg) {
  __shared__ unsigned short Vs[64 * 132];  // pad 132: 2-way-free column reads
  const int t0 = blockIdx.x * 64, h = blockIdx.y, b = blockIdx.z;
  const int tid = threadIdx.x;
  const int w = tid >> 6, lane = tid & 63;
#pragma unroll
  for (int m = 0; m < 4; ++m) {
    const int idx = m * 256 + tid;
    const int tr = idx >> 4, blk = idx & 15;
    const unsigned short* src = V + ((size_t)(b * Sv) + t0 + tr) * Hv + h * DHv + blk * 8;
    ushortx4 v0 = *(const ushortx4*)(src);
    ushortx4 v1 = *(const ushortx4*)(src + 4);
    *(ushortx4*)(Vs + tr * 132 + blk * 8) = v0;      // 8B-aligned (132*2=264)
    *(ushortx4*)(Vs + tr * 132 + blk * 8 + 4) = v1;
  }
  __syncthreads();
  const size_t obase = ((size_t)(b * NHv + h) * DHv) * Sv + t0;
#pragma unroll 4
  for (int p = 0; p < 32; ++p) {
    const int d = p * 4 + w;
    Vtg[obase + (size_t)d * Sv + lane] = Vs[lane * 132 + d];
  }
}

// Flash attention, bias + causal, NO-MAX softmax (logits bounded; exp<=e^10 fp32-safe).
// 64 Q rows/block (768 blocks: load-balanced, reverted from the QBLK=128 experiment
// whose 384-block grid put the critical path on the longest block at ~50% machine
// utilization). 4 waves x 16 rows; K/Vt double-buffered, staged one KV-tile ahead;
// T5 setprio around MFMA clusters.
__global__ __launch_bounds__(256) void attn_kernel(
    const unsigned short* __restrict__ Qg, const unsigned short* __restrict__ Kg,
    const unsigned short* __restrict__ Vtg, const float* __restrict__ bias,
    unsigned short* __restrict__ Og) {
  __shared__ __align__(16) unsigned short Ks[2][64 * 128];   // [key][d], 16-blk swizzle
  __shared__ __align__(16) unsigned short Vt[2][128 * 64];   // [d][key], 8-blk swizzle
  __shared__ __align__(16) unsigned short Ps[4 * 16 * 64];

  const int xb = blockIdx.x;
  const int qt = (xb & 1) ? (23 - (xb >> 1)) : (xb >> 1);
  const int h = blockIdx.y, b = blockIdx.z;
  const int q0 = qt * 64;
  const int tid = threadIdx.x;
  const int w = tid >> 6, lane = tid & 63;
  const int quad = lane >> 4, l15 = lane & 15;

  const size_t bh_base = (size_t)(b * Sv) * Hv + (size_t)h * DHv;
  const size_t vt_base = ((size_t)(b * NHv + h) * DHv) * Sv;

  // Q frags (A-operand): row = q0 + w*16 + l15, k = kk*32 + quad*8 + j
  short8 qf[4];
  {
    const unsigned short* qbase = Qg + bh_base + (size_t)(q0 + w * 16 + l15) * Hv;
#pragma unroll
    for (int kk = 0; kk < 4; ++kk)
      qf[kk] = *(const short8*)(qbase + kk * 32 + quad * 8);
  }

  floatx4 o[8];
#pragma unroll
  for (int n = 0; n < 8; ++n)
#pragma unroll
    for (int r = 0; r < 4; ++r) o[n][r] = 0.0f;
  float lrow[4] = {0.0f, 0.0f, 0.0f, 0.0f};

  const float* biasbase = bias + (size_t)(b * NHv + h) * Sv * Sv;
  unsigned short* pw = Ps + w * 1024;

  // staging descriptors
  size_t koff[4], voff[4]; int lbs[4];
#pragma unroll
  for (int m = 0; m < 4; ++m) {
    const int sK = m * 256 + tid;
    const int rK = sK >> 4, bK = sK & 15;          // Ks: 64 rows x 16 blocks
    koff[m] = bh_base + (size_t)rK * Hv + ((bK ^ (rK & 15)) * 8);
    const int sV = m * 256 + tid;
    const int rV = sV >> 3, bV = sV & 7;           // Vt: 128 rows x 8 blocks
    voff[m] = vt_base + (size_t)rV * Sv + ((bV ^ (rV & 7)) * 8);
    lbs[m] = (m * 256 + w * 64) * 8;               // wave-uniform
  }

  // preload bias tile 0
  float bv[4][4];
#pragma unroll
  for (int r = 0; r < 4; ++r) {
    const size_t brow = (size_t)(q0 + w * 16 + quad * 4 + r) * Sv;
#pragma unroll
    for (int j = 0; j < 4; ++j) bv[r][j] = biasbase[brow + j * 16 + l15];
  }

  // prologue: stage KV tile 0 into buffer 0
#pragma unroll
  for (int m = 0; m < 4; ++m) {
    async_copy16(Kg + koff[m], Ks[0] + lbs[m]);
    async_copy16(Vtg + voff[m], Vt[0] + lbs[m]);
  }
  __syncthreads();

  for (int kt = 0; kt <= qt; ++kt) {
    const int k0 = kt * 64;
    const int cur = kt & 1;

    // stage next KV tile into the other buffer (in flight across compute)
    if (kt < qt) {
      const int k1 = k0 + 64;
#pragma unroll
      for (int m = 0; m < 4; ++m) {
        async_copy16(Kg + koff[m] + (size_t)k1 * Hv, Ks[cur ^ 1] + lbs[m]);
        async_copy16(Vtg + voff[m] + k1, Vt[cur ^ 1] + lbs[m]);
      }
    }

    // prefetch next bias tile (consumed next iteration)
    const int kn = (kt < qt) ? k0 + 64 : k0;
    float bvn[4][4];
#pragma unroll
    for (int r = 0; r < 4; ++r) {
      const size_t brow = (size_t)(q0 + w * 16 + quad * 4 + r) * Sv;
#pragma unroll
      for (int j = 0; j < 4; ++j) bvn[r][j] = biasbase[brow + kn + j * 16 + l15];
    }

    // S = Q K^T
    const unsigned short* ks_ = Ks[cur];
    const unsigned short* vt_ = Vt[cur];
    floatx4 sacc[4];
    __builtin_amdgcn_s_setprio(1);
#pragma unroll
    for (int j = 0; j < 4; ++j) {
#pragma unroll
      for (int r = 0; r < 4; ++r) sacc[j][r] = 0.0f;
      const int kr = j * 16 + l15;
#pragma unroll
      for (int kk = 0; kk < 4; ++kk) {
        const int g = kk * 4 + quad;
        short8 bfrag = *(const short8*)(ks_ + kr * 128 + (g ^ (kr & 15)) * 8);
        sacc[j] = MFMA16(qf[kk], bfrag, sacc[j]);
      }
    }
    __builtin_amdgcn_s_setprio(0);

    // p = exp(s + bias) (no max-shift), causal zero on diagonal tile; store P
    const bool diag = (kt == qt);
#pragma unroll
    for (int r = 0; r < 4; ++r) {
      const int qrow = q0 + w * 16 + quad * 4 + r;
      const int prow = quad * 4 + r;
      float acc_l = 0.0f;
#pragma unroll
      for (int j = 0; j < 4; ++j) {
        const int col = j * 16 + l15;
        float p = __expf(sacc[j][r] + bv[r][j]);
        if (diag && (k0 + col) > qrow) p = 0.0f;
        acc_l += p;
        pw[prow * 64 + ((col >> 3) ^ (prow & 7)) * 8 + (col & 7)] = f2bf(p);
      }
      lrow[r] += acc_l;
    }
#pragma unroll
    for (int r = 0; r < 4; ++r)
#pragma unroll
      for (int j = 0; j < 4; ++j) bv[r][j] = bvn[r][j];

    // O += P @ V
    __builtin_amdgcn_s_setprio(1);
#pragma unroll
    for (int kk = 0; kk < 2; ++kk) {
      const int g = kk * 4 + quad;
      short8 pa = *(const short8*)(pw + l15 * 64 + (g ^ (l15 & 7)) * 8);
#pragma unroll
      for (int n = 0; n < 8; ++n) {
        const int dr = n * 16 + l15;
        short8 vbf = *(const short8*)(vt_ + dr * 64 + (g ^ (dr & 7)) * 8);
        o[n] = MFMA16(pa, vbf, o[n]);
      }
    }
    __builtin_amdgcn_s_setprio(0);

    __syncthreads();  // KV[cur] reads done; next tile's loads have landed
  }

  // epilogue: reduce l across the 16 lanes holding each row, normalize, store
#pragma unroll
  for (int r = 0; r < 4; ++r) {
    float ls = lrow[r];
#pragma unroll
    for (int off = 1; off < 16; off <<= 1) ls += __shfl_xor(ls, off, 64);
    const float inv = 1.0f / ls;
    const int qrow = q0 + w * 16 + quad * 4 + r;
    const size_t rowbase = bh_base + (size_t)qrow * Hv;
#pragma unroll
    for (int n = 0; n < 8; ++n)
      Og[rowbase + n * 16 + l15] = f2bf(o[n][r] * inv);
  }
}

extern "C" void kernel_launch(void* const* d_in, const int* in_sizes, int n_in,
                              void* d_out, int out_size, void* d_ws, size_t ws_size,
                              hipStream_t stream) {
  const float* x = (const float*)d_in[0];
  const float* bias = (const float*)d_in[1];
  const float* Wq = (const float*)d_in[2];
  const float* Wk = (const float*)d_in[3];
  const float* Wv = (const float*)d_in[4];
  const float* Wo = (const float*)d_in[5];
  float* out = (float*)d_out;

  unsigned short* xb = (unsigned short*)d_ws;          // xb reused as Vt after QKV GEMM
  unsigned short* wqb = xb + (size_t)Mv * Hv;
  unsigned short* wkb = wqb + (size_t)Hv * Hv;
  unsigned short* wvb = wkb + (size_t)Hv * Hv;
  unsigned short* wob = wvb + (size_t)Hv * Hv;
  unsigned short* qb = wob + (size_t)Hv * Hv;
  unsigned short* kb = qb + (size_t)Mv * Hv;
  unsigned short* vb = kb + (size_t)Mv * Hv;
  unsigned short* ob = vb + (size_t)Mv * Hv;
  unsigned short* vtb = xb;  // x bf16 is dead after the QKV GEMM
  const size_t needed = ((size_t)Mv * Hv * 5 + (size_t)Hv * Hv * 4) * 2;
  if (ws_size < needed) return;

  const int cvt_n = (Mv * Hv) / 4 + Hv * Hv;
  cvt_all_kernel<<<dim3(cvt_n / 256), 256, 0, stream>>>(
      x, Wq, Wk, Wv, Wo, xb, wqb, wkb, wvb, wob);

  // Q,K,V = x @ W{q,k,v}^T (bf16 out), fused; 96x128 tiles -> 512 blocks (2/CU)
  qkv_fused_kernel<<<dim3(16, 32), 256, 0, stream>>>(
      xb, wqb, wkb, wvb, qb, kb, vb);

  // global V^T for async attention staging
  vtrans_kernel<<<dim3(24, 16, 2), 256, 0, stream>>>(vb, vtb);

  // 64 Q rows per block -> 24 q-tiles (balanced 768-block grid)
  attn_kernel<<<dim3(24, NHv, Bv), 256, 0, stream>>>(qb, kb, vtb, bias, ob);

  // out = attn @ Wo^T (fp32), 96x128 tiles -> 512 blocks (2/CU)
  gemm_bt_kernel<96, true><<<dim3(16, 32), 256, 0, stream>>>(ob, wob, out);
}